// Round 15
// baseline (145.315 us; speedup 1.0000x reference)
//
#include <hip/hip_runtime.h>

typedef short v8s __attribute__((ext_vector_type(8)));
typedef float v4f __attribute__((ext_vector_type(4)));
typedef unsigned short u16;
typedef unsigned int u32;
typedef u16 v4u __attribute__((ext_vector_type(4)));

#define SS 4096
#define DD 256
#define QB 128
#define KVB 32

__device__ __forceinline__ u16 f2bf(float f) {
  u32 u = __builtin_bit_cast(u32, f);
  return (u16)((u + 0x7FFFu + ((u >> 16) & 1u)) >> 16);
}

__device__ __forceinline__ float bf2f(u16 h) {
  u32 u = ((u32)h) << 16;
  return __builtin_bit_cast(float, u);
}

__device__ __forceinline__ void gload16(const u16* g, u16* l) {
  __builtin_amdgcn_global_load_lds((const __attribute__((address_space(1))) u32*)g,
                                   (__attribute__((address_space(3))) u32*)l, 16, 0, 0);
}

// ---- transpose + cast weights: wt[p][n][k] = W_p[k][n] in bf16 ----
__global__ void wcast_kernel(const float* __restrict__ Wq, const float* __restrict__ Wk,
                             const float* __restrict__ Wv, u16* __restrict__ wt) {
  int f = blockIdx.x * 256 + threadIdx.x;   // 3*65536 total
  int p = f >> 16, rem = f & 65535, n = rem >> 8, k = rem & 255;
  const float* W = (p == 0) ? Wq : ((p == 1) ? Wk : Wv);
  wt[f] = f2bf(W[k * 256 + n]);
}

// ---- QKV projection: 512 blocks x 32 tokens -> 2 blocks/CU (occupancy fix) ----
__global__ __launch_bounds__(256) void proj_kernel(
    const float* __restrict__ x, const u16* __restrict__ wt,
    const float* __restrict__ bq, const float* __restrict__ bk, const float* __restrict__ bv,
    u16* __restrict__ qg, u16* __restrict__ kg, u16* __restrict__ vtg) {
  __shared__ u16 xs[256 * 40];   // 20 KB: x-tile staging (16 KB) / V-transpose buffer
  const int tid = threadIdx.x;
  const int lane = tid & 63, w = tid >> 6, g = lane >> 4, l15 = lane & 15;
  const int tok0 = blockIdx.x * 32;

  // stage x tile [32 tok][256] as bf16, swizzled
#pragma unroll
  for (int it = 0; it < 4; ++it) {
    int idx = it * 256 + tid;
    int r = idx >> 5, d0 = (idx & 31) << 3;
    const float* src = x + (size_t)(tok0 + r) * DD + d0;
    float4 a = *(const float4*)src;
    float4 bb = *(const float4*)(src + 4);
    v8s pk;
    pk[0] = (short)f2bf(a.x);  pk[1] = (short)f2bf(a.y);
    pk[2] = (short)f2bf(a.z);  pk[3] = (short)f2bf(a.w);
    pk[4] = (short)f2bf(bb.x); pk[5] = (short)f2bf(bb.y);
    pk[6] = (short)f2bf(bb.z); pk[7] = (short)f2bf(bb.w);
    *(v8s*)(xs + r * DD + (((d0 >> 3) ^ (r & 7)) << 3)) = pk;
  }
  __syncthreads();

  v8s af[2][8];
#pragma unroll
  for (int m = 0; m < 2; ++m) {
    const int row = 16 * m + l15;
#pragma unroll
    for (int c = 0; c < 8; ++c)
      af[m][c] = *(const v8s*)(xs + row * DD + ((((4 * c + g) ^ (row & 7))) << 3));
  }
  __syncthreads();   // xs dead for all waves (af hoisted) -> reusable as vls

  const float SCL = 0.0625f * 1.44269504088896f;  // 1/sqrt(D) * log2(e)
  for (int p = 0; p < 3; ++p) {
    const u16* wbase = wt + p * 65536;
    const float* bias = (p == 0) ? bq : ((p == 1) ? bk : bv);
    v4f acc[2][4];
    const v4f vzero = {0.f, 0.f, 0.f, 0.f};
#pragma unroll
    for (int m = 0; m < 2; ++m)
#pragma unroll
      for (int t = 0; t < 4; ++t) acc[m][t] = vzero;
#pragma unroll
    for (int t = 0; t < 4; ++t) {
      const int n = 64 * w + 16 * t + l15;
      const u16* wrow = wbase + n * 256;
#pragma unroll
      for (int c = 0; c < 8; ++c) {
        v8s bf = *(const v8s*)(wrow + 8 * g + 32 * c);
#pragma unroll
        for (int m = 0; m < 2; ++m)
          acc[m][t] = __builtin_amdgcn_mfma_f32_16x16x32_bf16(af[m][c], bf, acc[m][t], 0, 0, 0);
      }
    }
    if (p == 0) {
#pragma unroll
      for (int t = 0; t < 4; ++t) {
        int n = 64 * w + 16 * t + l15;
        float bb = bias[n];
#pragma unroll
        for (int m = 0; m < 2; ++m)
#pragma unroll
          for (int r = 0; r < 4; ++r)
            qg[(size_t)(tok0 + 16 * m + 4 * g + r) * DD + n] = f2bf((acc[m][t][r] + bb) * SCL);
      }
    } else if (p == 1) {
#pragma unroll
      for (int t = 0; t < 4; ++t) {
        int n = 64 * w + 16 * t + l15;
        float bb = bias[n];
#pragma unroll
        for (int m = 0; m < 2; ++m)
#pragma unroll
          for (int r = 0; r < 4; ++r)
            kg[(size_t)(tok0 + 16 * m + 4 * g + r) * DD + n] = f2bf(acc[m][t][r] + bb);
      }
    } else {
      // V: write [n][token] tile into LDS (stride 40 u16 -> bank-spread), then
      // coalesced 16-B global stores of the transposed tile.
      u16* vls = xs;             // [256 n][40 u16 stride], tokens 0..31 dense
#pragma unroll
      for (int t = 0; t < 4; ++t) {
        int n = 64 * w + 16 * t + l15;
        float bb = bias[n];
#pragma unroll
        for (int m = 0; m < 2; ++m) {
          v4u pk;
#pragma unroll
          for (int r = 0; r < 4; ++r) pk[r] = f2bf(acc[m][t][r] + bb);
          *(v4u*)(vls + n * 40 + 16 * m + 4 * g) = pk;
        }
      }
      __syncthreads();
      const int b = tok0 >> 12;
      const int s0 = tok0 & 4095;
#pragma unroll
      for (int pass = 0; pass < 4; ++pass) {
        int idx = pass * 256 + tid;
        int n = idx >> 2, sc = (idx & 3) * 8;
        *(v8s*)(vtg + (size_t)(b * DD + n) * SS + s0 + sc) = *(const v8s*)(vls + n * 40 + sc);
      }
    }
  }
}

// ---- flash attention: 4 waves x 32 q-rows, KVB=32, double-buffered K/V,
// ---- 64 KB LDS, 2 blocks/CU; chunked conflict-free LDS; bf16 partials out.
#define STAGE(kt_, buf_)                                                          \
  {                                                                               \
    const int kt__ = (kt_);                                                       \
    u16* kd = kb + (buf_)*8192;                                                   \
    u16* vd = vt + (buf_)*8192;                                                   \
    _Pragma("unroll")                                                             \
    for (int it = 0; it < 4; ++it) {                                              \
      int idx = it * 256 + tid;                                                   \
      int ch = idx >> 6, tt = ch >> 3, cc = ch & 7;                               \
      int ll = (idx >> 2) & 15, gp = (idx & 3) ^ (ll & 3);                        \
      gload16(kbase + (size_t)(kt__ * KVB + 16 * tt + ll) * DD + 8 * (4 * cc + gp), \
              kd + idx * 8);                                                      \
    }                                                                             \
    _Pragma("unroll")                                                             \
    for (int it = 0; it < 4; ++it) {                                              \
      int idx = it * 256 + tid;                                                   \
      int tt = idx >> 6, ll = (idx >> 2) & 15, gp = (idx & 3) ^ (ll & 3);         \
      gload16(vbase + (size_t)(16 * tt + ll) * SS + kt__ * KVB + 8 * gp,          \
              vd + idx * 8);                                                      \
    }                                                                             \
  }

__global__ __attribute__((amdgpu_flat_work_group_size(256, 256),
                          amdgpu_waves_per_eu(2))) void attn_kernel(
    const u16* __restrict__ qg, const u16* __restrict__ kg, const u16* __restrict__ vtg,
    u16* __restrict__ opart, float* __restrict__ ml, int nsplit, int nblk) {
  extern __shared__ u16 sm[];
  u16* kb = sm;                 // [2][16 chunks][512 u16] K tiles (32 KB)
  u16* vt = sm + 16384;         // [2][16 chunks][512 u16] V^T tiles (32 KB)

  const int bid = blockIdx.x;
  const int lg = (bid & 7) * (nblk >> 3) + (bid >> 3);  // XCD-contiguous logical id
  const int slice = lg >> 7;
  const int rem = lg & 127;
  const int b = rem >> 5;
  const int qt = rem & 31;
  const int NT = (SS / KVB) / nsplit;
  const int koff = slice * (SS / nsplit);

  const int tid = threadIdx.x;
  const int lane = tid & 63, w = tid >> 6, g = lane >> 4, l15 = lane & 15;
  const int slot = ((l15 << 2) | (g ^ (l15 & 3))) << 3;  // u16 offset within chunk

  const u16* qbase = qg + (size_t)(b * SS + qt * QB) * DD;
  const u16* kbase = kg + (size_t)(b * SS + koff) * DD;
  const u16* vbase = vtg + (size_t)b * DD * SS + koff;

  STAGE(0, 0);                  // tile-0 prefetch flies under Q loads

  // Q B-fragments straight from global (L2-resident, one-time)
  v8s qf[2][8];
#pragma unroll
  for (int j = 0; j < 2; ++j) {
    const u16* qr = qbase + (size_t)(32 * w + 16 * j + l15) * DD;
#pragma unroll
    for (int c = 0; c < 8; ++c)
      qf[j][c] = *(const v8s*)(qr + ((4 * c + g) << 3));
  }

  float mrow[2], lrow[2];
  v4f oacc[2][16];
  const v4f vzero = {0.f, 0.f, 0.f, 0.f};
#pragma unroll
  for (int j = 0; j < 2; ++j) { mrow[j] = -1e30f; lrow[j] = 0.f; }
#pragma unroll
  for (int m = 0; m < 2; ++m)
#pragma unroll
    for (int t = 0; t < 16; ++t) oacc[m][t] = vzero;

  for (int kt = 0; kt < NT; ++kt) {
    const int cur = kt & 1;
    __syncthreads();                       // stage(kt) landed; prev-tile reads done
    if (kt + 1 < NT) STAGE(kt + 1, cur ^ 1);   // prefetch flies under compute
    const u16* kc = kb + cur * 8192;
    const u16* vc = vt + cur * 8192;

    // S^T = K @ Q^T : lane holds S[key=16t+4g+r][qrow=32w+16j+l15]
    v4f sacc[2][2];
#pragma unroll
    for (int t = 0; t < 2; ++t)
#pragma unroll
      for (int j = 0; j < 2; ++j) sacc[t][j] = vzero;
    __builtin_amdgcn_s_setprio(1);
#pragma unroll
    for (int c = 0; c < 8; ++c) {
#pragma unroll
      for (int t = 0; t < 2; ++t) {
        v8s kf = *(const v8s*)(kc + (((t << 3) | c) << 9) + slot);
#pragma unroll
        for (int j = 0; j < 2; ++j)
          sacc[t][j] = __builtin_amdgcn_mfma_f32_16x16x32_bf16(kf, qf[j][c], sacc[t][j], 0, 0, 0);
      }
    }
    __builtin_amdgcn_s_setprio(0);

    // lane-local max check (no shuffles in common path)
    float tml[2];
#pragma unroll
    for (int j = 0; j < 2; ++j) {
      float a0 = fmaxf(fmaxf(sacc[0][j][0], sacc[0][j][1]), fmaxf(sacc[0][j][2], sacc[0][j][3]));
      float a1 = fmaxf(fmaxf(sacc[1][j][0], sacc[1][j][1]), fmaxf(sacc[1][j][2], sacc[1][j][3]));
      tml[j] = fmaxf(a0, a1);
    }
    const bool ok = (tml[0] - mrow[0] <= 11.0f) && (tml[1] - mrow[1] <= 11.0f);
    if (!__all(ok)) {
      float sc[2];
#pragma unroll
      for (int j = 0; j < 2; ++j) {
        float t0 = fmaxf(tml[j], __shfl_xor(tml[j], 16));
        t0 = fmaxf(t0, __shfl_xor(t0, 32));
        float nm = fmaxf(mrow[j], t0);
        sc[j] = exp2f(mrow[j] - nm);
        mrow[j] = nm;
        lrow[j] *= sc[j];
      }
#pragma unroll
      for (int m = 0; m < 2; ++m) {
#pragma unroll
        for (int r = 0; r < 4; ++r) {
          float s4 = __shfl(sc[m], (lane & 48) | (4 * g + r));
#pragma unroll
          for (int t = 0; t < 16; ++t) oacc[m][t][r] *= s4;
        }
      }
    }

    // P = exp2(S - m) -> bf16 pairs (cvt_pk) -> PV A-frags via register shuffle.
    v8s pa[2];
#pragma unroll
    for (int j = 0; j < 2; ++j) {
      u32 m32[4];
      float ls = 0.f;
#pragma unroll
      for (int t = 0; t < 2; ++t) {
        float e0 = exp2f(sacc[t][j][0] - mrow[j]);
        float e1 = exp2f(sacc[t][j][1] - mrow[j]);
        float e2 = exp2f(sacc[t][j][2] - mrow[j]);
        float e3 = exp2f(sacc[t][j][3] - mrow[j]);
        ls += (e0 + e1) + (e2 + e3);
        u32 lo, hi;
        asm("v_cvt_pk_bf16_f32 %0, %1, %2" : "=v"(lo) : "v"(e0), "v"(e1));
        asm("v_cvt_pk_bf16_f32 %0, %1, %2" : "=v"(hi) : "v"(e2), "v"(e3));
        m32[2 * t] = lo;
        m32[2 * t + 1] = hi;
      }
      lrow[j] += ls;                       // lane-partial; reduced once at epilogue
      const int la = l15 | ((g & 1) << 5);
      const int lb = la + 16;
      u32 A0 = (u32)__shfl((int)m32[0], la), A2 = (u32)__shfl((int)m32[2], la);
      u32 B1 = (u32)__shfl((int)m32[1], la), B3 = (u32)__shfl((int)m32[3], la);
      u32 C0 = (u32)__shfl((int)m32[0], lb), C2 = (u32)__shfl((int)m32[2], lb);
      u32 D1 = (u32)__shfl((int)m32[1], lb), D3 = (u32)__shfl((int)m32[3], lb);
      const bool sel = ((g >> 1) & 1) != 0;
      union { v8s v; u32 u[4]; } P;
      P.u[0] = sel ? A2 : A0;
      P.u[1] = sel ? B3 : B1;
      P.u[2] = sel ? C2 : C0;
      P.u[3] = sel ? D3 : D1;
      pa[j] = P.v;
    }

    // O += P @ V  (A = P in regs, B = V^T tile, chunked conflict-free reads)
    __builtin_amdgcn_s_setprio(1);
#pragma unroll
    for (int t = 0; t < 16; ++t) {
      v8s bvv = *(const v8s*)(vc + (t << 9) + slot);
#pragma unroll
      for (int m = 0; m < 2; ++m)
        oacc[m][t] = __builtin_amdgcn_mfma_f32_16x16x32_bf16(pa[m], bvv, oacc[m][t], 0, 0, 0);
    }
    __builtin_amdgcn_s_setprio(0);
  }

  // epilogue: reduce lane-partial l, write bf16 UNNORMALIZED partial O + (m,l)
#pragma unroll
  for (int j = 0; j < 2; ++j) {
    lrow[j] += __shfl_xor(lrow[j], 16);
    lrow[j] += __shfl_xor(lrow[j], 32);
  }
  u16* opb = opart + (size_t)slice * 4194304;
  const size_t rb = (size_t)b * SS + (size_t)qt * QB;
  if (g == 0) {
#pragma unroll
    for (int j = 0; j < 2; ++j) {
      const size_t rowg = rb + 32 * w + 16 * j + l15;
      float2 v2 = make_float2(mrow[j], lrow[j]);
      *(float2*)(ml + ((size_t)slice * 16384 + rowg) * 2) = v2;
    }
  }
#pragma unroll
  for (int m = 0; m < 2; ++m)
#pragma unroll
    for (int t = 0; t < 16; ++t)
#pragma unroll
      for (int r = 0; r < 4; ++r)
        opb[(rb + 32 * w + 16 * m + 4 * g + r) * DD + 16 * t + l15] = f2bf(oacc[m][t][r]);
}

// ---- merge bf16 kv-split partials -> f32 output ----
__global__ __launch_bounds__(256) void combine_kernel(
    float* __restrict__ out, const u16* __restrict__ opart,
    const float* __restrict__ ml, int nsplit) {
  const int tid = threadIdx.x;
  const size_t row = (size_t)blockIdx.x * 4 + (tid >> 6);
  const int d = (tid & 63) * 4;
  float2 mls[4];
  float mm = -1e30f;
#pragma unroll
  for (int s = 0; s < 4; ++s) {
    if (s < nsplit) {
      mls[s] = *(const float2*)(ml + ((size_t)s * 16384 + row) * 2);
      mm = fmaxf(mm, mls[s].x);
    }
  }
  float l = 0.f;
  float4 acc = {0.f, 0.f, 0.f, 0.f};
#pragma unroll
  for (int s = 0; s < 4; ++s) {
    if (s < nsplit) {
      float a = exp2f(mls[s].x - mm);
      v4u h = *(const v4u*)(opart + (size_t)s * 4194304 + row * DD + d);
      l += a * mls[s].y;
      acc.x += a * bf2f(h[0]);
      acc.y += a * bf2f(h[1]);
      acc.z += a * bf2f(h[2]);
      acc.w += a * bf2f(h[3]);
    }
  }
  float inv = 1.0f / l;
  acc.x *= inv; acc.y *= inv; acc.z *= inv; acc.w *= inv;
  *(float4*)(out + row * DD + d) = acc;
}

extern "C" void kernel_launch(void* const* d_in, const int* in_sizes, int n_in,
                              void* d_out, int out_size, void* d_ws, size_t ws_size,
                              hipStream_t stream) {
  const float* x  = (const float*)d_in[0];
  const float* Wq = (const float*)d_in[1];
  const float* bq = (const float*)d_in[2];
  const float* Wk = (const float*)d_in[3];
  const float* bk = (const float*)d_in[4];
  const float* Wv = (const float*)d_in[5];
  const float* bv = (const float*)d_in[6];
  float* out = (float*)d_out;
  char* ws = (char*)d_ws;

  u16* wt    = (u16*)ws;                                  //   393,216 B
  u16* qg    = (u16*)(ws + 393216);                       // 8,388,608 B
  u16* kg    = (u16*)(ws + 393216 + 8388608);             // 8,388,608 B
  u16* vtg   = (u16*)(ws + 393216 + 2 * 8388608);         // 8,388,608 B
  float* ml  = (float*)(ws + 25559040);                   //   524,288 B (4 slices)
  u16* op    = (u16*)(ws + 26083328);                     // 4 x 8,388,608 B bf16 partials
  const size_t need4 = 26083328ull + 4ull * 8388608ull;   // ~59.6 MB
  const size_t need2 = 26083328ull + 2ull * 8388608ull;   // ~42.9 MB
  const int nsplit = (ws_size >= need4) ? 4 : ((ws_size >= need2) ? 2 : 1);
  const int nblk = 128 * nsplit;

  (void)hipFuncSetAttribute((const void*)attn_kernel,
                            hipFuncAttributeMaxDynamicSharedMemorySize, 65536);

  wcast_kernel<<<dim3(768), dim3(256), 0, stream>>>(Wq, Wk, Wv, wt);
  proj_kernel<<<dim3(512), dim3(256), 0, stream>>>(x, wt, bq, bk, bv, qg, kg, vtg);
  attn_kernel<<<dim3(nblk), dim3(256), 65536, stream>>>(qg, kg, vtg, op, ml, nsplit, nblk);
  combine_kernel<<<dim3(4096), dim3(256), 0, stream>>>(out, op, ml, nsplit);
}

// Round 16
// 138.956 us; speedup vs baseline: 1.0458x; 1.0458x over previous
//
#include <hip/hip_runtime.h>

typedef short v8s __attribute__((ext_vector_type(8)));
typedef float v4f __attribute__((ext_vector_type(4)));
typedef unsigned short u16;
typedef unsigned int u32;
typedef u16 v4u __attribute__((ext_vector_type(4)));

#define SS 4096
#define DD 256
#define QB 128
#define KVB 32

__device__ __forceinline__ u16 f2bf(float f) {
  u32 u = __builtin_bit_cast(u32, f);
  return (u16)((u + 0x7FFFu + ((u >> 16) & 1u)) >> 16);
}

__device__ __forceinline__ float bf2f(u16 h) {
  u32 u = ((u32)h) << 16;
  return __builtin_bit_cast(float, u);
}

__device__ __forceinline__ void gload16(const u16* g, u16* l) {
  __builtin_amdgcn_global_load_lds((const __attribute__((address_space(1))) u32*)g,
                                   (__attribute__((address_space(3))) u32*)l, 16, 0, 0);
}

// ---- transpose + cast weights: wt[p][n][k] = W_p[k][n] in bf16 ----
__global__ void wcast_kernel(const float* __restrict__ Wq, const float* __restrict__ Wk,
                             const float* __restrict__ Wv, u16* __restrict__ wt) {
  int f = blockIdx.x * 256 + threadIdx.x;   // 3*65536 total
  int p = f >> 16, rem = f & 65535, n = rem >> 8, k = rem & 255;
  const float* W = (p == 0) ? Wq : ((p == 1) ? Wk : Wv);
  wt[f] = f2bf(W[k * 256 + n]);
}

// ---- QKV projection; V staged through LDS for coalesced transposed stores ----
__global__ __launch_bounds__(256) void proj_kernel(
    const float* __restrict__ x, const u16* __restrict__ wt,
    const float* __restrict__ bq, const float* __restrict__ bk, const float* __restrict__ bv,
    u16* __restrict__ qg, u16* __restrict__ kg, u16* __restrict__ vtg) {
  __shared__ u16 xs[64 * 256];
  const int tid = threadIdx.x;
  const int lane = tid & 63, w = tid >> 6, g = lane >> 4, l15 = lane & 15;
  const int tok0 = blockIdx.x * 64;

#pragma unroll
  for (int it = 0; it < 8; ++it) {
    int idx = it * 256 + tid;
    int r = idx >> 5, d0 = (idx & 31) << 3;
    const float* src = x + (size_t)(tok0 + r) * DD + d0;
    float4 a = *(const float4*)src;
    float4 bb = *(const float4*)(src + 4);
    v8s pk;
    pk[0] = (short)f2bf(a.x);  pk[1] = (short)f2bf(a.y);
    pk[2] = (short)f2bf(a.z);  pk[3] = (short)f2bf(a.w);
    pk[4] = (short)f2bf(bb.x); pk[5] = (short)f2bf(bb.y);
    pk[6] = (short)f2bf(bb.z); pk[7] = (short)f2bf(bb.w);
    *(v8s*)(xs + r * DD + (((d0 >> 3) ^ (r & 7)) << 3)) = pk;
  }
  __syncthreads();

  v8s af[4][8];
#pragma unroll
  for (int m = 0; m < 4; ++m) {
    const int row = 16 * m + l15;
#pragma unroll
    for (int c = 0; c < 8; ++c)
      af[m][c] = *(const v8s*)(xs + row * DD + ((((4 * c + g) ^ (row & 7))) << 3));
  }
  __syncthreads();   // xs dead for all waves (af hoisted) -> reusable as vls

  const float SCL = 0.0625f * 1.44269504088896f;  // 1/sqrt(D) * log2(e)
  for (int p = 0; p < 3; ++p) {
    const u16* wbase = wt + p * 65536;
    const float* bias = (p == 0) ? bq : ((p == 1) ? bk : bv);
    v4f acc[4][4];
    const v4f vzero = {0.f, 0.f, 0.f, 0.f};
#pragma unroll
    for (int m = 0; m < 4; ++m)
#pragma unroll
      for (int t = 0; t < 4; ++t) acc[m][t] = vzero;
#pragma unroll
    for (int t = 0; t < 4; ++t) {
      const int n = 64 * w + 16 * t + l15;
      const u16* wrow = wbase + n * 256;
#pragma unroll
      for (int c = 0; c < 8; ++c) {
        v8s bf = *(const v8s*)(wrow + 8 * g + 32 * c);
#pragma unroll
        for (int m = 0; m < 4; ++m)
          acc[m][t] = __builtin_amdgcn_mfma_f32_16x16x32_bf16(af[m][c], bf, acc[m][t], 0, 0, 0);
      }
    }
    if (p == 0) {
#pragma unroll
      for (int t = 0; t < 4; ++t) {
        int n = 64 * w + 16 * t + l15;
        float bb = bias[n];
#pragma unroll
        for (int m = 0; m < 4; ++m)
#pragma unroll
          for (int r = 0; r < 4; ++r)
            qg[(size_t)(tok0 + 16 * m + 4 * g + r) * DD + n] = f2bf((acc[m][t][r] + bb) * SCL);
      }
    } else if (p == 1) {
#pragma unroll
      for (int t = 0; t < 4; ++t) {
        int n = 64 * w + 16 * t + l15;
        float bb = bias[n];
#pragma unroll
        for (int m = 0; m < 4; ++m)
#pragma unroll
          for (int r = 0; r < 4; ++r)
            kg[(size_t)(tok0 + 16 * m + 4 * g + r) * DD + n] = f2bf(acc[m][t][r] + bb);
      }
    } else {
      // V: write [n][token] tile into LDS (xs reused), then coalesced stores
      u16* vls = xs;             // [256 n][64 tok], (n&3)<<4 XOR to spread banks
#pragma unroll
      for (int t = 0; t < 4; ++t) {
        int n = 64 * w + 16 * t + l15;
        float bb = bias[n];
#pragma unroll
        for (int m = 0; m < 4; ++m) {
          v4u pk;
#pragma unroll
          for (int r = 0; r < 4; ++r) pk[r] = f2bf(acc[m][t][r] + bb);
          *(v4u*)(vls + n * 64 + ((16 * m + 4 * g) ^ ((n & 3) << 4))) = pk;
        }
      }
      __syncthreads();
      const int b = tok0 >> 12;
      const int s0 = tok0 & 4095;
#pragma unroll
      for (int pass = 0; pass < 8; ++pass) {
        int n = pass * 32 + (tid >> 3);
        int sc = (tid & 7) * 8;
        *(v8s*)(vtg + (size_t)(b * DD + n) * SS + s0 + sc) =
            *(const v8s*)(vls + n * 64 + (sc ^ ((n & 3) << 4)));
      }
    }
  }
}

// ---- flash attention: 4 waves x 32 q-rows, KVB=32, double-buffered K/V,
// ---- 64 KB LDS, 2 blocks/CU; chunked conflict-free LDS; bf16 partials out.
#define STAGE(kt_, buf_)                                                          \
  {                                                                               \
    const int kt__ = (kt_);                                                       \
    u16* kd = kb + (buf_)*8192;                                                   \
    u16* vd = vt + (buf_)*8192;                                                   \
    _Pragma("unroll")                                                             \
    for (int it = 0; it < 4; ++it) {                                              \
      int idx = it * 256 + tid;                                                   \
      int ch = idx >> 6, tt = ch >> 3, cc = ch & 7;                               \
      int ll = (idx >> 2) & 15, gp = (idx & 3) ^ (ll & 3);                        \
      gload16(kbase + (size_t)(kt__ * KVB + 16 * tt + ll) * DD + 8 * (4 * cc + gp), \
              kd + idx * 8);                                                      \
    }                                                                             \
    _Pragma("unroll")                                                             \
    for (int it = 0; it < 4; ++it) {                                              \
      int idx = it * 256 + tid;                                                   \
      int tt = idx >> 6, ll = (idx >> 2) & 15, gp = (idx & 3) ^ (ll & 3);         \
      gload16(vbase + (size_t)(16 * tt + ll) * SS + kt__ * KVB + 8 * gp,          \
              vd + idx * 8);                                                      \
    }                                                                             \
  }

__global__ __attribute__((amdgpu_flat_work_group_size(256, 256),
                          amdgpu_waves_per_eu(2))) void attn_kernel(
    const u16* __restrict__ qg, const u16* __restrict__ kg, const u16* __restrict__ vtg,
    u16* __restrict__ opart, float* __restrict__ ml, int nsplit, int nblk) {
  extern __shared__ u16 sm[];
  u16* kb = sm;                 // [2][16 chunks][512 u16] K tiles (32 KB)
  u16* vt = sm + 16384;         // [2][16 chunks][512 u16] V^T tiles (32 KB)

  const int bid = blockIdx.x;
  const int lg = (bid & 7) * (nblk >> 3) + (bid >> 3);  // XCD-contiguous logical id
  const int slice = lg >> 7;
  const int rem = lg & 127;
  const int b = rem >> 5;
  const int qt = rem & 31;
  const int NT = (SS / KVB) / nsplit;
  const int koff = slice * (SS / nsplit);

  const int tid = threadIdx.x;
  const int lane = tid & 63, w = tid >> 6, g = lane >> 4, l15 = lane & 15;
  const int slot = ((l15 << 2) | (g ^ (l15 & 3))) << 3;  // u16 offset within chunk

  const u16* qbase = qg + (size_t)(b * SS + qt * QB) * DD;
  const u16* kbase = kg + (size_t)(b * SS + koff) * DD;
  const u16* vbase = vtg + (size_t)b * DD * SS + koff;

  STAGE(0, 0);                  // tile-0 prefetch flies under Q loads

  // Q B-fragments straight from global (L2-resident, one-time)
  v8s qf[2][8];
#pragma unroll
  for (int j = 0; j < 2; ++j) {
    const u16* qr = qbase + (size_t)(32 * w + 16 * j + l15) * DD;
#pragma unroll
    for (int c = 0; c < 8; ++c)
      qf[j][c] = *(const v8s*)(qr + ((4 * c + g) << 3));
  }

  float mrow[2], lrow[2];
  v4f oacc[2][16];
  const v4f vzero = {0.f, 0.f, 0.f, 0.f};
#pragma unroll
  for (int j = 0; j < 2; ++j) { mrow[j] = -1e30f; lrow[j] = 0.f; }
#pragma unroll
  for (int m = 0; m < 2; ++m)
#pragma unroll
    for (int t = 0; t < 16; ++t) oacc[m][t] = vzero;

  for (int kt = 0; kt < NT; ++kt) {
    const int cur = kt & 1;
    __syncthreads();                       // stage(kt) landed; prev-tile reads done
    if (kt + 1 < NT) STAGE(kt + 1, cur ^ 1);   // prefetch flies under compute
    const u16* kc = kb + cur * 8192;
    const u16* vc = vt + cur * 8192;

    // S^T = K @ Q^T : lane holds S[key=16t+4g+r][qrow=32w+16j+l15]
    v4f sacc[2][2];
#pragma unroll
    for (int t = 0; t < 2; ++t)
#pragma unroll
      for (int j = 0; j < 2; ++j) sacc[t][j] = vzero;
    __builtin_amdgcn_s_setprio(1);
#pragma unroll
    for (int c = 0; c < 8; ++c) {
#pragma unroll
      for (int t = 0; t < 2; ++t) {
        v8s kf = *(const v8s*)(kc + (((t << 3) | c) << 9) + slot);
#pragma unroll
        for (int j = 0; j < 2; ++j)
          sacc[t][j] = __builtin_amdgcn_mfma_f32_16x16x32_bf16(kf, qf[j][c], sacc[t][j], 0, 0, 0);
      }
    }
    __builtin_amdgcn_s_setprio(0);

    // lane-local max check (no shuffles in common path)
    float tml[2];
#pragma unroll
    for (int j = 0; j < 2; ++j) {
      float a0 = fmaxf(fmaxf(sacc[0][j][0], sacc[0][j][1]), fmaxf(sacc[0][j][2], sacc[0][j][3]));
      float a1 = fmaxf(fmaxf(sacc[1][j][0], sacc[1][j][1]), fmaxf(sacc[1][j][2], sacc[1][j][3]));
      tml[j] = fmaxf(a0, a1);
    }
    const bool ok = (tml[0] - mrow[0] <= 11.0f) && (tml[1] - mrow[1] <= 11.0f);
    if (!__all(ok)) {
      float sc[2];
#pragma unroll
      for (int j = 0; j < 2; ++j) {
        float t0 = fmaxf(tml[j], __shfl_xor(tml[j], 16));
        t0 = fmaxf(t0, __shfl_xor(t0, 32));
        float nm = fmaxf(mrow[j], t0);
        sc[j] = exp2f(mrow[j] - nm);
        mrow[j] = nm;
        lrow[j] *= sc[j];
      }
#pragma unroll
      for (int m = 0; m < 2; ++m) {
#pragma unroll
        for (int r = 0; r < 4; ++r) {
          float s4 = __shfl(sc[m], (lane & 48) | (4 * g + r));
#pragma unroll
          for (int t = 0; t < 16; ++t) oacc[m][t][r] *= s4;
        }
      }
    }

    // P = exp2(S - m) -> bf16 pairs (cvt_pk) -> PV A-frags via register shuffle.
    v8s pa[2];
#pragma unroll
    for (int j = 0; j < 2; ++j) {
      u32 m32[4];
      float ls = 0.f;
#pragma unroll
      for (int t = 0; t < 2; ++t) {
        float e0 = exp2f(sacc[t][j][0] - mrow[j]);
        float e1 = exp2f(sacc[t][j][1] - mrow[j]);
        float e2 = exp2f(sacc[t][j][2] - mrow[j]);
        float e3 = exp2f(sacc[t][j][3] - mrow[j]);
        ls += (e0 + e1) + (e2 + e3);
        u32 lo, hi;
        asm("v_cvt_pk_bf16_f32 %0, %1, %2" : "=v"(lo) : "v"(e0), "v"(e1));
        asm("v_cvt_pk_bf16_f32 %0, %1, %2" : "=v"(hi) : "v"(e2), "v"(e3));
        m32[2 * t] = lo;
        m32[2 * t + 1] = hi;
      }
      lrow[j] += ls;                       // lane-partial; reduced once at epilogue
      const int la = l15 | ((g & 1) << 5);
      const int lb = la + 16;
      u32 A0 = (u32)__shfl((int)m32[0], la), A2 = (u32)__shfl((int)m32[2], la);
      u32 B1 = (u32)__shfl((int)m32[1], la), B3 = (u32)__shfl((int)m32[3], la);
      u32 C0 = (u32)__shfl((int)m32[0], lb), C2 = (u32)__shfl((int)m32[2], lb);
      u32 D1 = (u32)__shfl((int)m32[1], lb), D3 = (u32)__shfl((int)m32[3], lb);
      const bool sel = ((g >> 1) & 1) != 0;
      union { v8s v; u32 u[4]; } P;
      P.u[0] = sel ? A2 : A0;
      P.u[1] = sel ? B3 : B1;
      P.u[2] = sel ? C2 : C0;
      P.u[3] = sel ? D3 : D1;
      pa[j] = P.v;
    }

    // O += P @ V  (A = P in regs, B = V^T tile, chunked conflict-free reads)
    __builtin_amdgcn_s_setprio(1);
#pragma unroll
    for (int t = 0; t < 16; ++t) {
      v8s bvv = *(const v8s*)(vc + (t << 9) + slot);
#pragma unroll
      for (int m = 0; m < 2; ++m)
        oacc[m][t] = __builtin_amdgcn_mfma_f32_16x16x32_bf16(pa[m], bvv, oacc[m][t], 0, 0, 0);
    }
    __builtin_amdgcn_s_setprio(0);
  }

  // epilogue: reduce lane-partial l, write bf16 UNNORMALIZED partial O + (m,l)
#pragma unroll
  for (int j = 0; j < 2; ++j) {
    lrow[j] += __shfl_xor(lrow[j], 16);
    lrow[j] += __shfl_xor(lrow[j], 32);
  }
  u16* opb = opart + (size_t)slice * 4194304;
  const size_t rb = (size_t)b * SS + (size_t)qt * QB;
  if (g == 0) {
#pragma unroll
    for (int j = 0; j < 2; ++j) {
      const size_t rowg = rb + 32 * w + 16 * j + l15;
      float2 v2 = make_float2(mrow[j], lrow[j]);
      *(float2*)(ml + ((size_t)slice * 16384 + rowg) * 2) = v2;
    }
  }
#pragma unroll
  for (int m = 0; m < 2; ++m)
#pragma unroll
    for (int t = 0; t < 16; ++t)
#pragma unroll
      for (int r = 0; r < 4; ++r)
        opb[(rb + 32 * w + 16 * m + 4 * g + r) * DD + 16 * t + l15] = f2bf(oacc[m][t][r]);
}

// ---- merge bf16 kv-split partials -> f32 output ----
__global__ __launch_bounds__(256) void combine_kernel(
    float* __restrict__ out, const u16* __restrict__ opart,
    const float* __restrict__ ml, int nsplit) {
  const int tid = threadIdx.x;
  const size_t row = (size_t)blockIdx.x * 4 + (tid >> 6);
  const int d = (tid & 63) * 4;
  float2 mls[4];
  float mm = -1e30f;
#pragma unroll
  for (int s = 0; s < 4; ++s) {
    if (s < nsplit) {
      mls[s] = *(const float2*)(ml + ((size_t)s * 16384 + row) * 2);
      mm = fmaxf(mm, mls[s].x);
    }
  }
  float l = 0.f;
  float4 acc = {0.f, 0.f, 0.f, 0.f};
#pragma unroll
  for (int s = 0; s < 4; ++s) {
    if (s < nsplit) {
      float a = exp2f(mls[s].x - mm);
      v4u h = *(const v4u*)(opart + (size_t)s * 4194304 + row * DD + d);
      l += a * mls[s].y;
      acc.x += a * bf2f(h[0]);
      acc.y += a * bf2f(h[1]);
      acc.z += a * bf2f(h[2]);
      acc.w += a * bf2f(h[3]);
    }
  }
  float inv = 1.0f / l;
  acc.x *= inv; acc.y *= inv; acc.z *= inv; acc.w *= inv;
  *(float4*)(out + row * DD + d) = acc;
}

extern "C" void kernel_launch(void* const* d_in, const int* in_sizes, int n_in,
                              void* d_out, int out_size, void* d_ws, size_t ws_size,
                              hipStream_t stream) {
  const float* x  = (const float*)d_in[0];
  const float* Wq = (const float*)d_in[1];
  const float* bq = (const float*)d_in[2];
  const float* Wk = (const float*)d_in[3];
  const float* bk = (const float*)d_in[4];
  const float* Wv = (const float*)d_in[5];
  const float* bv = (const float*)d_in[6];
  float* out = (float*)d_out;
  char* ws = (char*)d_ws;

  u16* wt    = (u16*)ws;                                  //   393,216 B
  u16* qg    = (u16*)(ws + 393216);                       // 8,388,608 B
  u16* kg    = (u16*)(ws + 393216 + 8388608);             // 8,388,608 B
  u16* vtg   = (u16*)(ws + 393216 + 2 * 8388608);         // 8,388,608 B
  float* ml  = (float*)(ws + 25559040);                   //   524,288 B (4 slices)
  u16* op    = (u16*)(ws + 26083328);                     // 4 x 8,388,608 B bf16 partials
  const size_t need4 = 26083328ull + 4ull * 8388608ull;   // ~59.6 MB
  const size_t need2 = 26083328ull + 2ull * 8388608ull;   // ~42.9 MB
  const int nsplit = (ws_size >= need4) ? 4 : ((ws_size >= need2) ? 2 : 1);
  const int nblk = 128 * nsplit;

  (void)hipFuncSetAttribute((const void*)attn_kernel,
                            hipFuncAttributeMaxDynamicSharedMemorySize, 65536);

  wcast_kernel<<<dim3(768), dim3(256), 0, stream>>>(Wq, Wk, Wv, wt);
  proj_kernel<<<dim3(256), dim3(256), 0, stream>>>(x, wt, bq, bk, bv, qg, kg, vtg);
  attn_kernel<<<dim3(nblk), dim3(256), 65536, stream>>>(qg, kg, vtg, op, ml, nsplit, nblk);
  combine_kernel<<<dim3(4096), dim3(256), 0, stream>>>(out, op, ml, nsplit);
}